// Round 12
// baseline (208.157 us; speedup 1.0000x reference)
//
#include <hip/hip_runtime.h>
#include <cstdint>

#define DEV __device__ __forceinline__

typedef __bf16 bf16x8 __attribute__((ext_vector_type(8)));
typedef float f32x4 __attribute__((ext_vector_type(4)));
typedef float f32x16 __attribute__((ext_vector_type(16)));
typedef uint32_t u32x4 __attribute__((ext_vector_type(4)));

// ---------- bf16 helpers (RNE) ----------
DEV uint16_t f2b(float f) {
  uint32_t u = __builtin_bit_cast(uint32_t, f);
  u = u + 0x7fffu + ((u >> 16) & 1u);
  return (uint16_t)(u >> 16);
}
DEV float b2f(uint16_t h) { return __builtin_bit_cast(float, (uint32_t)h << 16); }
DEV uint32_t pk2(float lo, float hi) {
  return (uint32_t)f2b(lo) | ((uint32_t)f2b(hi) << 16);
}

DEV f32x16 mfma32(bf16x8 a, bf16x8 b, f32x16 c) {
  return __builtin_amdgcn_mfma_f32_32x32x16_bf16(a, b, c, 0, 0, 0);
}

// ---------- async global->LDS (16B per lane) ----------
DEV void gload16(const void* g, void* s) {
  __builtin_amdgcn_global_load_lds((const __attribute__((address_space(1))) uint32_t*)g,
                                   (__attribute__((address_space(3))) uint32_t*)s, 16, 0, 0);
}

// ---------- fused prep: x->bf16 | W_qkv^T | W_out^T | rope tables ----------
__global__ __launch_bounds__(256) void k_prep(const float* __restrict__ X,
                                              uint16_t* __restrict__ Xb,
                                              const float* __restrict__ Wqkv,
                                              uint16_t* __restrict__ Wqkvt,
                                              const float* __restrict__ Wout,
                                              uint16_t* __restrict__ Woutt,
                                              float* __restrict__ rc,
                                              float* __restrict__ rs) {
  __shared__ uint16_t sh[64][68];
  const int tid = threadIdx.x;
  const int blk = blockIdx.x;
  if (blk < 8192) {
    const int i = blk * 256 + tid;
    float4 v = ((const float4*)X)[i];
    uint64_t packed = (uint64_t)f2b(v.x) | ((uint64_t)f2b(v.y) << 16) |
                      ((uint64_t)f2b(v.z) << 32) | ((uint64_t)f2b(v.w) << 48);
    ((uint64_t*)Xb)[i] = packed;
  } else if (blk < 9216) {
    const bool big = blk < 8960;
    const int t = big ? (blk - 8192) : (blk - 8960);
    const int ntx = big ? 48 : 16;
    const int C = big ? 3072 : 1024;
    const int R = 1024;
    const float* W = big ? Wqkv : Wout;
    uint16_t* Wt = big ? Wqkvt : Woutt;
    const int bc = (t % ntx) * 64, br = (t / ntx) * 64;
#pragma unroll
    for (int it = 0; it < 16; ++it) {
      const int e = it * 256 + tid;
      const int i = e >> 6, j = e & 63;
      sh[j][i] = f2b(W[(size_t)(br + i) * C + bc + j]);
    }
    __syncthreads();
#pragma unroll
    for (int it = 0; it < 2; ++it) {
      const int e = it * 256 + tid;
      const int j = e >> 3, i8 = (e & 7) * 8;
      uint16_t tmp[8];
#pragma unroll
      for (int k = 0; k < 8; ++k) tmp[k] = sh[j][i8 + k];
      *(uint4*)&Wt[(size_t)(bc + j) * R + br + i8] = *(uint4*)tmp;
    }
  } else {
    const int idx = (blk - 9216) * 256 + tid;  // T*32
    const int t = idx >> 5, j = idx & 31;
    float inv = powf(10000.f, -(float)j / 32.f);
    float ang = (float)t * inv;
    rc[idx] = cosf(ang);
    rs[idx] = sinf(ang);
  }
}

// Gather global-key/query tiles: Kg/Qg[bh][32][64], Vtg[bh][64][32]
__global__ __launch_bounds__(256) void k_gather(const uint16_t* __restrict__ Qd,
                                                const uint16_t* __restrict__ Kd,
                                                const uint16_t* __restrict__ Vt,
                                                uint16_t* __restrict__ Qg,
                                                uint16_t* __restrict__ Kg,
                                                uint16_t* __restrict__ Vtg) {
  const int tid = threadIdx.x;
  const int bh = blockIdx.x;
  {
    const int g = tid >> 3, d8 = (tid & 7) * 8;
    const size_t src = ((size_t)(bh << 11) + g * 64) * 64 + d8;
    const size_t dst = ((size_t)bh * 32 + g) * 64 + d8;
    *(uint4*)&Kg[dst] = *(const uint4*)&Kd[src];
    *(uint4*)&Qg[dst] = *(const uint4*)&Qd[src];
  }
  {
    const int d = tid >> 2, g8 = (tid & 3) * 8;
    uint16_t tmp[8];
#pragma unroll
    for (int j = 0; j < 8; ++j) tmp[j] = Vt[((size_t)bh * 64 + d) * 2048 + (size_t)(g8 + j) * 64];
    *(uint4*)&Vtg[((size_t)bh * 64 + d) * 32 + g8] = *(uint4*)tmp;
  }
}

// ---------- 128x128 single-buffer 2-phase bf16 MFMA GEMM1 (round-4 K-loop) ----------
// XCD-chunked bm-fastest (round-11 proven). __launch_bounds__(256,5): cap VGPR at
// ~102 so 5 blocks/CU fit (LDS 32KB allows exactly 5) — +25% co-resident TLP to
// cover the per-tile barrier drain. Epilogue = round-9 proven.
__global__ __launch_bounds__(256, 5) void gemmQKV(
    const uint16_t* __restrict__ A, const uint16_t* __restrict__ Bt,
    int M, int N, int K,
    uint16_t* __restrict__ Qd, uint16_t* __restrict__ Kd, uint16_t* __restrict__ Vt,
    const float* __restrict__ rc, const float* __restrict__ rs) {
  __shared__ __align__(16) uint16_t smem[2 * 128 * 64];  // sA | sB; reused for V transpose
  uint16_t* sA = smem;
  uint16_t* sB = smem + 128 * 64;
  const int tid = threadIdx.x;
  const int w = tid >> 6, lane = tid & 63;
  const int wm = w >> 1, wn = w & 1;
  const int ln = lane & 31, hi = lane >> 5;

  // XCD chunk (nwg=1536, 192/XCD): 8 bm-rows per XCD, bm-fastest order.
  const int orig = blockIdx.y * 24 + blockIdx.x;
  const int xcd = orig & 7, q = orig >> 3;
  const int bm = (xcd * 8 + (q & 7)) * 128;
  const int bn = (q >> 3) * 128;

  f32x16 acc[2][2] = {};
  const int lsw = (ln & 7) << 4;  // read-side XOR swizzle (byte)

  for (int kt = 0; kt < K; kt += 64) {
#pragma unroll
    for (int r = 0; r < 4; ++r) {
      const int slot = r * 256 + tid;
      const int row = slot >> 3, c8 = slot & 7;
      const int gc = kt + ((c8 ^ (row & 7)) << 3);  // pre-swizzled source column
      gload16(A + (size_t)(bm + row) * K + gc, (char*)sA + (r * 256 + (tid & ~63)) * 16);
      gload16(Bt + (size_t)(bn + row) * K + gc, (char*)sB + (r * 256 + (tid & ~63)) * 16);
    }
    __syncthreads();
#pragma unroll
    for (int ks = 0; ks < 4; ++ks) {
      const int cb = ks * 32 + hi * 16;
      bf16x8 af[2], bf[2];
#pragma unroll
      for (int mi = 0; mi < 2; ++mi) {
        const int row = wm * 64 + mi * 32 + ln;
        af[mi] = *(const bf16x8*)((const char*)sA + row * 128 + (cb ^ lsw));
      }
#pragma unroll
      for (int ni = 0; ni < 2; ++ni) {
        const int row = wn * 64 + ni * 32 + ln;
        bf[ni] = *(const bf16x8*)((const char*)sB + row * 128 + (cb ^ lsw));
      }
#pragma unroll
      for (int mi = 0; mi < 2; ++mi)
#pragma unroll
        for (int ni = 0; ni < 2; ++ni)
          acc[mi][ni] = mfma32(af[mi], bf[ni], acc[mi][ni]);
    }
    __syncthreads();
  }

  // C layout (32x32): col = lane&31, row = (r&3) + 8*(r>>2) + 4*hi
  if (bn >= 2048) {
    // ---- V block: LDS-bounce transpose, coalesced Vt store ----
#pragma unroll
    for (int mi = 0; mi < 2; ++mi)
#pragma unroll
      for (int ni = 0; ni < 2; ++ni) {
        const int col = wn * 64 + ni * 32 + ln;
#pragma unroll
        for (int r = 0; r < 16; ++r) {
          const int crow = (r & 3) + 8 * (r >> 2) + 4 * hi;
          smem[(wm * 64 + mi * 32 + crow) * 128 + col] = f2b(acc[mi][ni][r]);
        }
      }
    __syncthreads();
    const int b = bm >> 11, t0 = bm & 2047;
    const int hbase = (bn - 2048) >> 6;
#pragma unroll
    for (int it = 0; it < 8; ++it) {
      const int idx = it * 256 + tid;
      const int dcol = idx & 127, tr8 = (idx >> 7) * 8;
      uint16_t tmp[8];
#pragma unroll
      for (int j = 0; j < 8; ++j) tmp[j] = smem[(tr8 + j) * 128 + dcol];
      const int bh = b * 16 + hbase + (dcol >> 6), d = dcol & 63;
      *(uint4*)&Vt[((size_t)bh * 64 + d) * 2048 + t0 + tr8] = *(uint4*)tmp;
    }
  } else {
    // ---- Q/K block: RoPE + split-store (round-9 proven scattered stores) ----
#pragma unroll
    for (int mi = 0; mi < 2; ++mi) {
#pragma unroll
      for (int ni = 0; ni < 2; ++ni) {
        const int colb = bn + wn * 64 + ni * 32 + ln;
#pragma unroll
        for (int r = 0; r < 16; ++r) {
          const int crow = (r & 3) + 8 * (r >> 2) + 4 * hi;
          const int row = bm + wm * 64 + mi * 32 + crow;
          float val = acc[mi][ni][r];
          const int b = row >> 11, t = row & 2047;
          const float pv = __shfl_xor(val, 1);  // partner column (d^1)
          const int d = colb & 63, j = d >> 1;
          const float c = rc[t * 32 + j], s = rs[t * 32 + j];
          const float rv = (d & 1) ? (val * c + pv * s) : (val * c - pv * s);
          const int cc = colb & 1023, h = cc >> 6;
          uint16_t* dst = (colb < 1024) ? Qd : Kd;
          dst[((((size_t)b * 16 + h) * 2048 + t) << 6) + d] = f2b(rv);
        }
      }
    }
  }
}

// ---------- 128x128 single-buffer 2-phase GEMM2 + bm-fastest XCD chunk ----------
__global__ __launch_bounds__(256) void gemm128(
    const uint16_t* __restrict__ A, const uint16_t* __restrict__ Bt,
    int M, int N, int K, float* __restrict__ Cout, const float* __restrict__ bias) {
  __shared__ __align__(16) uint16_t sA[128 * 64];
  __shared__ __align__(16) uint16_t sB[128 * 64];
  const int tid = threadIdx.x;
  const int w = tid >> 6, lane = tid & 63;
  const int wm = w >> 1, wn = w & 1;
  const int ln = lane & 31, hi = lane >> 5;

  // XCD chunk (nwg=512, 64/XCD): 8 bm x 8 bn per XCD, bm-fastest (4MB set fits L2).
  const int orig = blockIdx.y * 8 + blockIdx.x;
  const int xcd = orig & 7, q = orig >> 3;
  const int bm = (xcd * 8 + (q & 7)) * 128;
  const int bn = (q >> 3) * 128;

  f32x16 acc[2][2] = {};
  const int lsw = (ln & 7) << 4;

  for (int kt = 0; kt < K; kt += 64) {
#pragma unroll
    for (int r = 0; r < 4; ++r) {
      const int slot = r * 256 + tid;
      const int row = slot >> 3, c8 = slot & 7;
      const int gc = kt + ((c8 ^ (row & 7)) << 3);
      gload16(A + (size_t)(bm + row) * K + gc, (char*)sA + (r * 256 + (tid & ~63)) * 16);
      gload16(Bt + (size_t)(bn + row) * K + gc, (char*)sB + (r * 256 + (tid & ~63)) * 16);
    }
    __syncthreads();
#pragma unroll
    for (int ks = 0; ks < 4; ++ks) {
      const int cb = ks * 32 + hi * 16;
      bf16x8 af[2], bf[2];
#pragma unroll
      for (int mi = 0; mi < 2; ++mi) {
        const int row = wm * 64 + mi * 32 + ln;
        af[mi] = *(const bf16x8*)((const char*)sA + row * 128 + (cb ^ lsw));
      }
#pragma unroll
      for (int ni = 0; ni < 2; ++ni) {
        const int row = wn * 64 + ni * 32 + ln;
        bf[ni] = *(const bf16x8*)((const char*)sB + row * 128 + (cb ^ lsw));
      }
#pragma unroll
      for (int mi = 0; mi < 2; ++mi)
#pragma unroll
        for (int ni = 0; ni < 2; ++ni)
          acc[mi][ni] = mfma32(af[mi], bf[ni], acc[mi][ni]);
    }
    __syncthreads();
  }

#pragma unroll
  for (int mi = 0; mi < 2; ++mi) {
#pragma unroll
    for (int ni = 0; ni < 2; ++ni) {
      const int colb = bn + wn * 64 + ni * 32 + ln;
#pragma unroll
      for (int r = 0; r < 16; ++r) {
        const int crow = (r & 3) + 8 * (r >> 2) + 4 * hi;
        const int row = bm + wm * 64 + mi * 32 + crow;
        Cout[(size_t)row * N + colb] = acc[mi][ni][r] + bias[colb];
      }
    }
  }
}

// ---------- MFMA flash-attention tile step (32x32x16, swapped QK^T) ----------
// T5: setprio(1) around MFMA clusters — attn blocks are independent multi-wave
// (m191 regime: +4-7%), unlike barrier-lockstep GEMM where it is null.
template <int MASK>
DEV void attn_tile(const uint16_t* __restrict__ kb_ptr, const uint16_t* __restrict__ v_ptr,
                   const int vrs, const int kb, const int qv, const int hi, const int ln,
                   const bf16x8 qf[4], float& m, float& l, f32x16& acc0, f32x16& acc1) {
  bf16x8 kf0 = *(const bf16x8*)&kb_ptr[ln * 64 + 0 + hi * 8];
  bf16x8 kf1 = *(const bf16x8*)&kb_ptr[ln * 64 + 16 + hi * 8];
  bf16x8 kf2 = *(const bf16x8*)&kb_ptr[ln * 64 + 32 + hi * 8];
  bf16x8 kf3 = *(const bf16x8*)&kb_ptr[ln * 64 + 48 + hi * 8];
  bf16x8 vf00 = *(const bf16x8*)&v_ptr[ln * vrs + hi * 8];
  bf16x8 vf01 = *(const bf16x8*)&v_ptr[ln * vrs + 16 + hi * 8];
  bf16x8 vf10 = *(const bf16x8*)&v_ptr[(32 + ln) * vrs + hi * 8];
  bf16x8 vf11 = *(const bf16x8*)&v_ptr[(32 + ln) * vrs + 16 + hi * 8];

  f32x16 sv = {};
  __builtin_amdgcn_s_setprio(1);
  sv = mfma32(kf0, qf[0], sv);
  sv = mfma32(kf1, qf[1], sv);
  sv = mfma32(kf2, qf[2], sv);
  sv = mfma32(kf3, qf[3], sv);
  __builtin_amdgcn_s_setprio(0);

  float s[16];
  float pm = -3.0e38f;
#pragma unroll
  for (int r = 0; r < 16; ++r) {
    const int crow = (r & 3) + 8 * (r >> 2) + 4 * hi;
    bool ok;
    if (MASK == 0) {
      const int key = kb + crow;
      ok = (key <= qv) && (key + 127 >= qv);
    } else if (MASK == 1) {
      ok = crow * 64 <= qv - 128;
    } else {
      const int key = kb + crow;
      ok = (key <= qv);
    }
    s[r] = ok ? sv[r] * 0.125f : -3.0e38f;
    pm = fmaxf(pm, s[r]);
  }
  pm = fmaxf(pm, __shfl_xor(pm, 32));

  if (__any(pm > m + 8.0f)) {
    const float mn = fmaxf(m, pm);
    const float f = __expf(m - mn);
#pragma unroll
    for (int r = 0; r < 16; ++r) {
      const int crow = (r & 3) + 8 * (r >> 2) + 4 * hi;
      const float fr = __shfl(f, crow);
      acc0[r] *= fr;
      acc1[r] *= fr;
    }
    l *= f;
    m = mn;
  }

  float p[16];
  float ps = 0.f;
#pragma unroll
  for (int r = 0; r < 16; ++r) {
    p[r] = __expf(s[r] - m);
    ps += p[r];
  }
  l += ps + __shfl_xor(ps, 32);

  const uint32_t q0a = pk2(p[0], p[1]), q0b = pk2(p[2], p[3]);
  const uint32_t q1a = pk2(p[4], p[5]), q1b = pk2(p[6], p[7]);
  const uint32_t q2a = pk2(p[8], p[9]), q2b = pk2(p[10], p[11]);
  const uint32_t q3a = pk2(p[12], p[13]), q3b = pk2(p[14], p[15]);
  const uint32_t p0a = __shfl_xor(q0a, 32), p0b = __shfl_xor(q0b, 32);
  const uint32_t p1a = __shfl_xor(q1a, 32), p1b = __shfl_xor(q1b, 32);
  const uint32_t p2a = __shfl_xor(q2a, 32), p2b = __shfl_xor(q2b, 32);
  const uint32_t p3a = __shfl_xor(q3a, 32), p3b = __shfl_xor(q3b, 32);
  u32x4 f0, f1;
  f0[0] = hi ? p1a : q0a; f0[1] = hi ? p1b : q0b; f0[2] = hi ? q1a : p0a; f0[3] = hi ? q1b : p0b;
  f1[0] = hi ? p3a : q2a; f1[1] = hi ? p3b : q2b; f1[2] = hi ? q3a : p2a; f1[3] = hi ? q3b : p2b;
  const bf16x8 pa0 = __builtin_bit_cast(bf16x8, f0);
  const bf16x8 pa1 = __builtin_bit_cast(bf16x8, f1);

  __builtin_amdgcn_s_setprio(1);
  acc0 = mfma32(pa0, vf00, acc0);
  acc0 = mfma32(pa1, vf01, acc0);
  acc1 = mfma32(pa0, vf10, acc1);
  acc1 = mfma32(pa1, vf11, acc1);
  __builtin_amdgcn_s_setprio(0);
}

// Fused attention: blocks [0,1024) = main sparse path (skips stores of global-query
// rows); blocks [1024,1088) = full-causal global-query rows (sole writer of those rows).
__global__ __launch_bounds__(256) void attn_fused(const uint16_t* __restrict__ Qd,
                                                  const uint16_t* __restrict__ Kd,
                                                  const uint16_t* __restrict__ Vt,
                                                  const uint16_t* __restrict__ Kg,
                                                  const uint16_t* __restrict__ Vtg,
                                                  const uint16_t* __restrict__ Qg,
                                                  uint16_t* __restrict__ O) {
  __shared__ float accL[4][32][64];
  __shared__ float mL[4][32];
  __shared__ float lL[4][32];
  const int tid = threadIdx.x;
  const int lane = tid & 63, hi = lane >> 5, ln = lane & 31;

  if (blockIdx.x < 1024) {
    // ---- main sparse path ----
    const int wid = blockIdx.x * 4 + (tid >> 6);
    const int bh = wid >> 6, qt = wid & 63;
    const int qb = qt * 32;
    const int qv = qb + ln;

    bf16x8 qf[4];
#pragma unroll
    for (int i = 0; i < 4; ++i)
      qf[i] = *(const bf16x8*)&Qd[((size_t)(bh << 11) + qv) * 64 + i * 16 + hi * 8];

    float m = -1e30f, l = 0.f;
    f32x16 acc0 = {}, acc1 = {};

    const int kb0 = qb >= 128 ? qb - 128 : 0;
    for (int kbb = kb0; kbb <= qb; kbb += 32)
      attn_tile<0>(Kd + ((size_t)(bh << 11) + kbb) * 64, Vt + (size_t)bh * 64 * 2048 + kbb, 2048,
                   kbb, qv, hi, ln, qf, m, l, acc0, acc1);
    if (qb >= 128)
      attn_tile<1>(Kg + (size_t)bh * 32 * 64, Vtg + (size_t)bh * 64 * 32, 32,
                   0, qv, hi, ln, qf, m, l, acc0, acc1);

    const float linv = 1.0f / l;
    const int b = bh >> 4, h = bh & 15;
    const int ocol = h * 64 + ln;
    const bool hasg = (qb & 63) == 0;  // this tile contains a global query row (crow 0)
#pragma unroll
    for (int r = 0; r < 16; ++r) {
      const int crow = (r & 3) + 8 * (r >> 2) + 4 * hi;
      // __shfl under FULL exec (divergent skip before it would read an inactive lane).
      const float sc = __shfl(linv, crow);
      if (hasg && crow == 0) continue;  // attn-global branch owns this row
      const size_t orow = (size_t)(b * 2048 + qb + crow);
      O[orow * 1024 + ocol] = f2b(acc0[r] * sc);
      O[orow * 1024 + ocol + 32] = f2b(acc1[r] * sc);
    }
  } else {
    // ---- global-query rows (t%64==0): full causal, 4 waves split K, LDS merge ----
    const int bh = blockIdx.x - 1024;
    const int wv = tid >> 6;
    const int qv = ln * 64;

    bf16x8 qf[4];
#pragma unroll
    for (int i = 0; i < 4; ++i)
      qf[i] = *(const bf16x8*)&Qg[((size_t)bh * 32 + ln) * 64 + i * 16 + hi * 8];

    float m = -1e30f, l = 0.f;
    f32x16 acc0 = {}, acc1 = {};
    for (int kt = wv; kt < 64; kt += 4) {
      const int kbb = kt * 32;
      attn_tile<2>(Kd + ((size_t)(bh << 11) + kbb) * 64, Vt + (size_t)bh * 64 * 2048 + kbb, 2048,
                   kbb, qv, hi, ln, qf, m, l, acc0, acc1);
    }

    if (hi == 0) {
      mL[wv][ln] = m;
      lL[wv][ln] = l;
    }
#pragma unroll
    for (int r = 0; r < 16; ++r) {
      const int crow = (r & 3) + 8 * (r >> 2) + 4 * hi;
      accL[wv][crow][ln] = acc0[r];
      accL[wv][crow][ln + 32] = acc1[r];
    }
    __syncthreads();

    const int q = tid >> 3, d0 = (tid & 7) * 8;
    float M = fmaxf(fmaxf(mL[0][q], mL[1][q]), fmaxf(mL[2][q], mL[3][q]));
    float L = 0.f;
    float v[8] = {};
#pragma unroll
    for (int w = 0; w < 4; ++w) {
      const float ew = __expf(mL[w][q] - M);
      L += lL[w][q] * ew;
#pragma unroll
      for (int j = 0; j < 8; ++j) v[j] += accL[w][q][d0 + j] * ew;
    }
    const float Li = 1.0f / L;
    const int b = bh >> 4, h = bh & 15;
    const size_t orow = (size_t)(b * 2048 + q * 64);
#pragma unroll
    for (int j = 0; j < 8; ++j) O[orow * 1024 + h * 64 + d0 + j] = f2b(v[j] * Li);
  }
}

// ---------- launch ----------
extern "C" void kernel_launch(void* const* d_in, const int* in_sizes, int n_in,
                              void* d_out, int out_size, void* d_ws, size_t ws_size,
                              hipStream_t stream) {
  const float* x = (const float*)d_in[0];
  const float* W_qkv = (const float*)d_in[1];
  const float* W_out = (const float*)d_in[2];
  const float* b_out = (const float*)d_in[3];

  char* ws = (char*)d_ws;
  size_t off = 0;
  auto alloc = [&](size_t bytes) {
    void* p = ws + off;
    off += (bytes + 255) & ~(size_t)255;
    return p;
  };
  uint16_t* xb = (uint16_t*)alloc(8192ull * 1024 * 2);     // x bf16 (reused as attn-out O)
  uint16_t* wqkvt = (uint16_t*)alloc(3072ull * 1024 * 2);  // W_qkv^T bf16
  uint16_t* woutt = (uint16_t*)alloc(1024ull * 1024 * 2);  // W_out^T bf16
  float* rc = (float*)alloc(2048ull * 32 * 4);
  float* rs = (float*)alloc(2048ull * 32 * 4);
  uint16_t* Qd = (uint16_t*)alloc(8192ull * 1024 * 2);
  uint16_t* Kd = (uint16_t*)alloc(8192ull * 1024 * 2);
  uint16_t* Vt = (uint16_t*)alloc(8192ull * 1024 * 2);     // V transposed [bh][64][2048]
  uint16_t* Qg = (uint16_t*)alloc(64ull * 32 * 64 * 2);
  uint16_t* Kg = (uint16_t*)alloc(64ull * 32 * 64 * 2);
  uint16_t* Vtg = (uint16_t*)alloc(64ull * 64 * 32 * 2);
  uint16_t* O = xb;  // alias: xb dead after GEMM1

  k_prep<<<9472, 256, 0, stream>>>(x, xb, W_qkv, wqkvt, W_out, woutt, rc, rs);

  gemmQKV<<<dim3(24, 64), 256, 0, stream>>>(xb, wqkvt, 8192, 3072, 1024,
                                            Qd, Kd, Vt, rc, rs);

  k_gather<<<64, 256, 0, stream>>>(Qd, Kd, Vt, Qg, Kg, Vtg);

  attn_fused<<<1088, 256, 0, stream>>>(Qd, Kd, Vt, Kg, Vtg, Qg, O);

  gemm128<<<dim3(8, 64), 256, 0, stream>>>(O, woutt, 8192, 1024, 1024,
                                           (float*)d_out, b_out);
}

// Round 13
// 157.175 us; speedup vs baseline: 1.3244x; 1.3244x over previous
//
#include <hip/hip_runtime.h>
#include <cstdint>

#define DEV __device__ __forceinline__

typedef __bf16 bf16x8 __attribute__((ext_vector_type(8)));
typedef float f32x4 __attribute__((ext_vector_type(4)));
typedef float f32x16 __attribute__((ext_vector_type(16)));
typedef uint32_t u32x4 __attribute__((ext_vector_type(4)));

// ---------- bf16 helpers (RNE) ----------
DEV uint16_t f2b(float f) {
  uint32_t u = __builtin_bit_cast(uint32_t, f);
  u = u + 0x7fffu + ((u >> 16) & 1u);
  return (uint16_t)(u >> 16);
}
DEV float b2f(uint16_t h) { return __builtin_bit_cast(float, (uint32_t)h << 16); }
DEV uint32_t pk2(float lo, float hi) {
  return (uint32_t)f2b(lo) | ((uint32_t)f2b(hi) << 16);
}

DEV f32x16 mfma32(bf16x8 a, bf16x8 b, f32x16 c) {
  return __builtin_amdgcn_mfma_f32_32x32x16_bf16(a, b, c, 0, 0, 0);
}

// ---------- async global->LDS (16B per lane) ----------
DEV void gload16(const void* g, void* s) {
  __builtin_amdgcn_global_load_lds((const __attribute__((address_space(1))) uint32_t*)g,
                                   (__attribute__((address_space(3))) uint32_t*)s, 16, 0, 0);
}

// ---------- fused prep: x->bf16 | W_qkv^T | W_out^T | rope tables ----------
__global__ __launch_bounds__(256) void k_prep(const float* __restrict__ X,
                                              uint16_t* __restrict__ Xb,
                                              const float* __restrict__ Wqkv,
                                              uint16_t* __restrict__ Wqkvt,
                                              const float* __restrict__ Wout,
                                              uint16_t* __restrict__ Woutt,
                                              float* __restrict__ rc,
                                              float* __restrict__ rs) {
  __shared__ uint16_t sh[64][68];
  const int tid = threadIdx.x;
  const int blk = blockIdx.x;
  if (blk < 8192) {
    const int i = blk * 256 + tid;
    float4 v = ((const float4*)X)[i];
    uint64_t packed = (uint64_t)f2b(v.x) | ((uint64_t)f2b(v.y) << 16) |
                      ((uint64_t)f2b(v.z) << 32) | ((uint64_t)f2b(v.w) << 48);
    ((uint64_t*)Xb)[i] = packed;
  } else if (blk < 9216) {
    const bool big = blk < 8960;
    const int t = big ? (blk - 8192) : (blk - 8960);
    const int ntx = big ? 48 : 16;
    const int C = big ? 3072 : 1024;
    const int R = 1024;
    const float* W = big ? Wqkv : Wout;
    uint16_t* Wt = big ? Wqkvt : Woutt;
    const int bc = (t % ntx) * 64, br = (t / ntx) * 64;
#pragma unroll
    for (int it = 0; it < 16; ++it) {
      const int e = it * 256 + tid;
      const int i = e >> 6, j = e & 63;
      sh[j][i] = f2b(W[(size_t)(br + i) * C + bc + j]);
    }
    __syncthreads();
#pragma unroll
    for (int it = 0; it < 2; ++it) {
      const int e = it * 256 + tid;
      const int j = e >> 3, i8 = (e & 7) * 8;
      uint16_t tmp[8];
#pragma unroll
      for (int k = 0; k < 8; ++k) tmp[k] = sh[j][i8 + k];
      *(uint4*)&Wt[(size_t)(bc + j) * R + br + i8] = *(uint4*)tmp;
    }
  } else {
    const int idx = (blk - 9216) * 256 + tid;  // T*32
    const int t = idx >> 5, j = idx & 31;
    float inv = powf(10000.f, -(float)j / 32.f);
    float ang = (float)t * inv;
    rc[idx] = cosf(ang);
    rs[idx] = sinf(ang);
  }
}

// Gather global-key/query tiles: Kg/Qg[bh][32][64], Vtg[bh][64][32]
__global__ __launch_bounds__(256) void k_gather(const uint16_t* __restrict__ Qd,
                                                const uint16_t* __restrict__ Kd,
                                                const uint16_t* __restrict__ Vt,
                                                uint16_t* __restrict__ Qg,
                                                uint16_t* __restrict__ Kg,
                                                uint16_t* __restrict__ Vtg) {
  const int tid = threadIdx.x;
  const int bh = blockIdx.x;
  {
    const int g = tid >> 3, d8 = (tid & 7) * 8;
    const size_t src = ((size_t)(bh << 11) + g * 64) * 64 + d8;
    const size_t dst = ((size_t)bh * 32 + g) * 64 + d8;
    *(uint4*)&Kg[dst] = *(const uint4*)&Kd[src];
    *(uint4*)&Qg[dst] = *(const uint4*)&Qd[src];
  }
  {
    const int d = tid >> 2, g8 = (tid & 3) * 8;
    uint16_t tmp[8];
#pragma unroll
    for (int j = 0; j < 8; ++j) tmp[j] = Vt[((size_t)bh * 64 + d) * 2048 + (size_t)(g8 + j) * 64];
    *(uint4*)&Vtg[((size_t)bh * 64 + d) * 32 + g8] = *(uint4*)tmp;
  }
}

// ---------- 128x128 single-buffer 2-phase bf16 MFMA GEMM1 (round-11 exact) ----------
// XCD-chunked bm-fastest. NO aggressive launch_bounds: (256,5) forced VGPR 104->48
// and spilled the accumulator to scratch (WRITE_SIZE 49->126MB, dur 77->129us).
// gfx950 occupancy steps at VGPR 64/128/256 — >4 waves/SIMD needs <=64 VGPR.
__global__ __launch_bounds__(256) void gemmQKV(
    const uint16_t* __restrict__ A, const uint16_t* __restrict__ Bt,
    int M, int N, int K,
    uint16_t* __restrict__ Qd, uint16_t* __restrict__ Kd, uint16_t* __restrict__ Vt,
    const float* __restrict__ rc, const float* __restrict__ rs) {
  __shared__ __align__(16) uint16_t smem[2 * 128 * 64];  // sA | sB; reused for V transpose
  uint16_t* sA = smem;
  uint16_t* sB = smem + 128 * 64;
  const int tid = threadIdx.x;
  const int w = tid >> 6, lane = tid & 63;
  const int wm = w >> 1, wn = w & 1;
  const int ln = lane & 31, hi = lane >> 5;

  // XCD chunk (nwg=1536, 192/XCD): 8 bm-rows per XCD, bm-fastest order.
  const int orig = blockIdx.y * 24 + blockIdx.x;
  const int xcd = orig & 7, q = orig >> 3;
  const int bm = (xcd * 8 + (q & 7)) * 128;
  const int bn = (q >> 3) * 128;

  f32x16 acc[2][2] = {};
  const int lsw = (ln & 7) << 4;  // read-side XOR swizzle (byte)

  for (int kt = 0; kt < K; kt += 64) {
#pragma unroll
    for (int r = 0; r < 4; ++r) {
      const int slot = r * 256 + tid;
      const int row = slot >> 3, c8 = slot & 7;
      const int gc = kt + ((c8 ^ (row & 7)) << 3);  // pre-swizzled source column
      gload16(A + (size_t)(bm + row) * K + gc, (char*)sA + (r * 256 + (tid & ~63)) * 16);
      gload16(Bt + (size_t)(bn + row) * K + gc, (char*)sB + (r * 256 + (tid & ~63)) * 16);
    }
    __syncthreads();
#pragma unroll
    for (int ks = 0; ks < 4; ++ks) {
      const int cb = ks * 32 + hi * 16;
      bf16x8 af[2], bf[2];
#pragma unroll
      for (int mi = 0; mi < 2; ++mi) {
        const int row = wm * 64 + mi * 32 + ln;
        af[mi] = *(const bf16x8*)((const char*)sA + row * 128 + (cb ^ lsw));
      }
#pragma unroll
      for (int ni = 0; ni < 2; ++ni) {
        const int row = wn * 64 + ni * 32 + ln;
        bf[ni] = *(const bf16x8*)((const char*)sB + row * 128 + (cb ^ lsw));
      }
#pragma unroll
      for (int mi = 0; mi < 2; ++mi)
#pragma unroll
        for (int ni = 0; ni < 2; ++ni)
          acc[mi][ni] = mfma32(af[mi], bf[ni], acc[mi][ni]);
    }
    __syncthreads();
  }

  // C layout (32x32): col = lane&31, row = (r&3) + 8*(r>>2) + 4*hi
  if (bn >= 2048) {
    // ---- V block: LDS-bounce transpose, coalesced Vt store ----
#pragma unroll
    for (int mi = 0; mi < 2; ++mi)
#pragma unroll
      for (int ni = 0; ni < 2; ++ni) {
        const int col = wn * 64 + ni * 32 + ln;
#pragma unroll
        for (int r = 0; r < 16; ++r) {
          const int crow = (r & 3) + 8 * (r >> 2) + 4 * hi;
          smem[(wm * 64 + mi * 32 + crow) * 128 + col] = f2b(acc[mi][ni][r]);
        }
      }
    __syncthreads();
    const int b = bm >> 11, t0 = bm & 2047;
    const int hbase = (bn - 2048) >> 6;
#pragma unroll
    for (int it = 0; it < 8; ++it) {
      const int idx = it * 256 + tid;
      const int dcol = idx & 127, tr8 = (idx >> 7) * 8;
      uint16_t tmp[8];
#pragma unroll
      for (int j = 0; j < 8; ++j) tmp[j] = smem[(tr8 + j) * 128 + dcol];
      const int bh = b * 16 + hbase + (dcol >> 6), d = dcol & 63;
      *(uint4*)&Vt[((size_t)bh * 64 + d) * 2048 + t0 + tr8] = *(uint4*)tmp;
    }
  } else {
    // ---- Q/K block: RoPE + split-store (round-9 proven scattered stores) ----
#pragma unroll
    for (int mi = 0; mi < 2; ++mi) {
#pragma unroll
      for (int ni = 0; ni < 2; ++ni) {
        const int colb = bn + wn * 64 + ni * 32 + ln;
#pragma unroll
        for (int r = 0; r < 16; ++r) {
          const int crow = (r & 3) + 8 * (r >> 2) + 4 * hi;
          const int row = bm + wm * 64 + mi * 32 + crow;
          float val = acc[mi][ni][r];
          const int b = row >> 11, t = row & 2047;
          const float pv = __shfl_xor(val, 1);  // partner column (d^1)
          const int d = colb & 63, j = d >> 1;
          const float c = rc[t * 32 + j], s = rs[t * 32 + j];
          const float rv = (d & 1) ? (val * c + pv * s) : (val * c - pv * s);
          const int cc = colb & 1023, h = cc >> 6;
          uint16_t* dst = (colb < 1024) ? Qd : Kd;
          dst[((((size_t)b * 16 + h) * 2048 + t) << 6) + d] = f2b(rv);
        }
      }
    }
  }
}

// ---------- 128x128 single-buffer 2-phase GEMM2 + bm-fastest XCD chunk ----------
__global__ __launch_bounds__(256) void gemm128(
    const uint16_t* __restrict__ A, const uint16_t* __restrict__ Bt,
    int M, int N, int K, float* __restrict__ Cout, const float* __restrict__ bias) {
  __shared__ __align__(16) uint16_t sA[128 * 64];
  __shared__ __align__(16) uint16_t sB[128 * 64];
  const int tid = threadIdx.x;
  const int w = tid >> 6, lane = tid & 63;
  const int wm = w >> 1, wn = w & 1;
  const int ln = lane & 31, hi = lane >> 5;

  // XCD chunk (nwg=512, 64/XCD): 8 bm x 8 bn per XCD, bm-fastest (4MB set fits L2).
  const int orig = blockIdx.y * 8 + blockIdx.x;
  const int xcd = orig & 7, q = orig >> 3;
  const int bm = (xcd * 8 + (q & 7)) * 128;
  const int bn = (q >> 3) * 128;

  f32x16 acc[2][2] = {};
  const int lsw = (ln & 7) << 4;

  for (int kt = 0; kt < K; kt += 64) {
#pragma unroll
    for (int r = 0; r < 4; ++r) {
      const int slot = r * 256 + tid;
      const int row = slot >> 3, c8 = slot & 7;
      const int gc = kt + ((c8 ^ (row & 7)) << 3);
      gload16(A + (size_t)(bm + row) * K + gc, (char*)sA + (r * 256 + (tid & ~63)) * 16);
      gload16(Bt + (size_t)(bn + row) * K + gc, (char*)sB + (r * 256 + (tid & ~63)) * 16);
    }
    __syncthreads();
#pragma unroll
    for (int ks = 0; ks < 4; ++ks) {
      const int cb = ks * 32 + hi * 16;
      bf16x8 af[2], bf[2];
#pragma unroll
      for (int mi = 0; mi < 2; ++mi) {
        const int row = wm * 64 + mi * 32 + ln;
        af[mi] = *(const bf16x8*)((const char*)sA + row * 128 + (cb ^ lsw));
      }
#pragma unroll
      for (int ni = 0; ni < 2; ++ni) {
        const int row = wn * 64 + ni * 32 + ln;
        bf[ni] = *(const bf16x8*)((const char*)sB + row * 128 + (cb ^ lsw));
      }
#pragma unroll
      for (int mi = 0; mi < 2; ++mi)
#pragma unroll
        for (int ni = 0; ni < 2; ++ni)
          acc[mi][ni] = mfma32(af[mi], bf[ni], acc[mi][ni]);
    }
    __syncthreads();
  }

#pragma unroll
  for (int mi = 0; mi < 2; ++mi) {
#pragma unroll
    for (int ni = 0; ni < 2; ++ni) {
      const int colb = bn + wn * 64 + ni * 32 + ln;
#pragma unroll
      for (int r = 0; r < 16; ++r) {
        const int crow = (r & 3) + 8 * (r >> 2) + 4 * hi;
        const int row = bm + wm * 64 + mi * 32 + crow;
        Cout[(size_t)row * N + colb] = acc[mi][ni][r] + bias[colb];
      }
    }
  }
}

// ---------- MFMA flash-attention tile step (32x32x16, swapped QK^T) ----------
// T5: setprio(1) around MFMA clusters — attn blocks are independent multi-wave
// (m191 regime), unlike barrier-lockstep GEMM where it is null.
template <int MASK>
DEV void attn_tile(const uint16_t* __restrict__ kb_ptr, const uint16_t* __restrict__ v_ptr,
                   const int vrs, const int kb, const int qv, const int hi, const int ln,
                   const bf16x8 qf[4], float& m, float& l, f32x16& acc0, f32x16& acc1) {
  bf16x8 kf0 = *(const bf16x8*)&kb_ptr[ln * 64 + 0 + hi * 8];
  bf16x8 kf1 = *(const bf16x8*)&kb_ptr[ln * 64 + 16 + hi * 8];
  bf16x8 kf2 = *(const bf16x8*)&kb_ptr[ln * 64 + 32 + hi * 8];
  bf16x8 kf3 = *(const bf16x8*)&kb_ptr[ln * 64 + 48 + hi * 8];
  bf16x8 vf00 = *(const bf16x8*)&v_ptr[ln * vrs + hi * 8];
  bf16x8 vf01 = *(const bf16x8*)&v_ptr[ln * vrs + 16 + hi * 8];
  bf16x8 vf10 = *(const bf16x8*)&v_ptr[(32 + ln) * vrs + hi * 8];
  bf16x8 vf11 = *(const bf16x8*)&v_ptr[(32 + ln) * vrs + 16 + hi * 8];

  f32x16 sv = {};
  __builtin_amdgcn_s_setprio(1);
  sv = mfma32(kf0, qf[0], sv);
  sv = mfma32(kf1, qf[1], sv);
  sv = mfma32(kf2, qf[2], sv);
  sv = mfma32(kf3, qf[3], sv);
  __builtin_amdgcn_s_setprio(0);

  float s[16];
  float pm = -3.0e38f;
#pragma unroll
  for (int r = 0; r < 16; ++r) {
    const int crow = (r & 3) + 8 * (r >> 2) + 4 * hi;
    bool ok;
    if (MASK == 0) {
      const int key = kb + crow;
      ok = (key <= qv) && (key + 127 >= qv);
    } else if (MASK == 1) {
      ok = crow * 64 <= qv - 128;
    } else {
      const int key = kb + crow;
      ok = (key <= qv);
    }
    s[r] = ok ? sv[r] * 0.125f : -3.0e38f;
    pm = fmaxf(pm, s[r]);
  }
  pm = fmaxf(pm, __shfl_xor(pm, 32));

  if (__any(pm > m + 8.0f)) {
    const float mn = fmaxf(m, pm);
    const float f = __expf(m - mn);
#pragma unroll
    for (int r = 0; r < 16; ++r) {
      const int crow = (r & 3) + 8 * (r >> 2) + 4 * hi;
      const float fr = __shfl(f, crow);
      acc0[r] *= fr;
      acc1[r] *= fr;
    }
    l *= f;
    m = mn;
  }

  float p[16];
  float ps = 0.f;
#pragma unroll
  for (int r = 0; r < 16; ++r) {
    p[r] = __expf(s[r] - m);
    ps += p[r];
  }
  l += ps + __shfl_xor(ps, 32);

  const uint32_t q0a = pk2(p[0], p[1]), q0b = pk2(p[2], p[3]);
  const uint32_t q1a = pk2(p[4], p[5]), q1b = pk2(p[6], p[7]);
  const uint32_t q2a = pk2(p[8], p[9]), q2b = pk2(p[10], p[11]);
  const uint32_t q3a = pk2(p[12], p[13]), q3b = pk2(p[14], p[15]);
  const uint32_t p0a = __shfl_xor(q0a, 32), p0b = __shfl_xor(q0b, 32);
  const uint32_t p1a = __shfl_xor(q1a, 32), p1b = __shfl_xor(q1b, 32);
  const uint32_t p2a = __shfl_xor(q2a, 32), p2b = __shfl_xor(q2b, 32);
  const uint32_t p3a = __shfl_xor(q3a, 32), p3b = __shfl_xor(q3b, 32);
  u32x4 f0, f1;
  f0[0] = hi ? p1a : q0a; f0[1] = hi ? p1b : q0b; f0[2] = hi ? q1a : p0a; f0[3] = hi ? q1b : p0b;
  f1[0] = hi ? p3a : q2a; f1[1] = hi ? p3b : q2b; f1[2] = hi ? q3a : p2a; f1[3] = hi ? q3b : p2b;
  const bf16x8 pa0 = __builtin_bit_cast(bf16x8, f0);
  const bf16x8 pa1 = __builtin_bit_cast(bf16x8, f1);

  __builtin_amdgcn_s_setprio(1);
  acc0 = mfma32(pa0, vf00, acc0);
  acc0 = mfma32(pa1, vf01, acc0);
  acc1 = mfma32(pa0, vf10, acc1);
  acc1 = mfma32(pa1, vf11, acc1);
  __builtin_amdgcn_s_setprio(0);
}

// Fused attention: blocks [0,1024) = main sparse path (skips stores of global-query
// rows); blocks [1024,1088) = full-causal global-query rows (sole writer of those rows).
__global__ __launch_bounds__(256) void attn_fused(const uint16_t* __restrict__ Qd,
                                                  const uint16_t* __restrict__ Kd,
                                                  const uint16_t* __restrict__ Vt,
                                                  const uint16_t* __restrict__ Kg,
                                                  const uint16_t* __restrict__ Vtg,
                                                  const uint16_t* __restrict__ Qg,
                                                  uint16_t* __restrict__ O) {
  __shared__ float accL[4][32][64];
  __shared__ float mL[4][32];
  __shared__ float lL[4][32];
  const int tid = threadIdx.x;
  const int lane = tid & 63, hi = lane >> 5, ln = lane & 31;

  if (blockIdx.x < 1024) {
    // ---- main sparse path ----
    const int wid = blockIdx.x * 4 + (tid >> 6);
    const int bh = wid >> 6, qt = wid & 63;
    const int qb = qt * 32;
    const int qv = qb + ln;

    bf16x8 qf[4];
#pragma unroll
    for (int i = 0; i < 4; ++i)
      qf[i] = *(const bf16x8*)&Qd[((size_t)(bh << 11) + qv) * 64 + i * 16 + hi * 8];

    float m = -1e30f, l = 0.f;
    f32x16 acc0 = {}, acc1 = {};

    const int kb0 = qb >= 128 ? qb - 128 : 0;
    for (int kbb = kb0; kbb <= qb; kbb += 32)
      attn_tile<0>(Kd + ((size_t)(bh << 11) + kbb) * 64, Vt + (size_t)bh * 64 * 2048 + kbb, 2048,
                   kbb, qv, hi, ln, qf, m, l, acc0, acc1);
    if (qb >= 128)
      attn_tile<1>(Kg + (size_t)bh * 32 * 64, Vtg + (size_t)bh * 64 * 32, 32,
                   0, qv, hi, ln, qf, m, l, acc0, acc1);

    const float linv = 1.0f / l;
    const int b = bh >> 4, h = bh & 15;
    const int ocol = h * 64 + ln;
    const bool hasg = (qb & 63) == 0;  // this tile contains a global query row (crow 0)
#pragma unroll
    for (int r = 0; r < 16; ++r) {
      const int crow = (r & 3) + 8 * (r >> 2) + 4 * hi;
      // __shfl under FULL exec (divergent skip before it would read an inactive lane).
      const float sc = __shfl(linv, crow);
      if (hasg && crow == 0) continue;  // attn-global branch owns this row
      const size_t orow = (size_t)(b * 2048 + qb + crow);
      O[orow * 1024 + ocol] = f2b(acc0[r] * sc);
      O[orow * 1024 + ocol + 32] = f2b(acc1[r] * sc);
    }
  } else {
    // ---- global-query rows (t%64==0): full causal, 4 waves split K, LDS merge ----
    const int bh = blockIdx.x - 1024;
    const int wv = tid >> 6;
    const int qv = ln * 64;

    bf16x8 qf[4];
#pragma unroll
    for (int i = 0; i < 4; ++i)
      qf[i] = *(const bf16x8*)&Qg[((size_t)bh * 32 + ln) * 64 + i * 16 + hi * 8];

    float m = -1e30f, l = 0.f;
    f32x16 acc0 = {}, acc1 = {};
    for (int kt = wv; kt < 64; kt += 4) {
      const int kbb = kt * 32;
      attn_tile<2>(Kd + ((size_t)(bh << 11) + kbb) * 64, Vt + (size_t)bh * 64 * 2048 + kbb, 2048,
                   kbb, qv, hi, ln, qf, m, l, acc0, acc1);
    }

    if (hi == 0) {
      mL[wv][ln] = m;
      lL[wv][ln] = l;
    }
#pragma unroll
    for (int r = 0; r < 16; ++r) {
      const int crow = (r & 3) + 8 * (r >> 2) + 4 * hi;
      accL[wv][crow][ln] = acc0[r];
      accL[wv][crow][ln + 32] = acc1[r];
    }
    __syncthreads();

    const int q = tid >> 3, d0 = (tid & 7) * 8;
    float M = fmaxf(fmaxf(mL[0][q], mL[1][q]), fmaxf(mL[2][q], mL[3][q]));
    float L = 0.f;
    float v[8] = {};
#pragma unroll
    for (int w = 0; w < 4; ++w) {
      const float ew = __expf(mL[w][q] - M);
      L += lL[w][q] * ew;
#pragma unroll
      for (int j = 0; j < 8; ++j) v[j] += accL[w][q][d0 + j] * ew;
    }
    const float Li = 1.0f / L;
    const int b = bh >> 4, h = bh & 15;
    const size_t orow = (size_t)(b * 2048 + q * 64);
#pragma unroll
    for (int j = 0; j < 8; ++j) O[orow * 1024 + h * 64 + d0 + j] = f2b(v[j] * Li);
  }
}

// ---------- launch ----------
extern "C" void kernel_launch(void* const* d_in, const int* in_sizes, int n_in,
                              void* d_out, int out_size, void* d_ws, size_t ws_size,
                              hipStream_t stream) {
  const float* x = (const float*)d_in[0];
  const float* W_qkv = (const float*)d_in[1];
  const float* W_out = (const float*)d_in[2];
  const float* b_out = (const float*)d_in[3];

  char* ws = (char*)d_ws;
  size_t off = 0;
  auto alloc = [&](size_t bytes) {
    void* p = ws + off;
    off += (bytes + 255) & ~(size_t)255;
    return p;
  };
  uint16_t* xb = (uint16_t*)alloc(8192ull * 1024 * 2);     // x bf16 (reused as attn-out O)
  uint16_t* wqkvt = (uint16_t*)alloc(3072ull * 1024 * 2);  // W_qkv^T bf16
  uint16_t* woutt = (uint16_t*)alloc(1024ull * 1024 * 2);  // W_out^T bf16
  float* rc = (float*)alloc(2048ull * 32 * 4);
  float* rs = (float*)alloc(2048ull * 32 * 4);
  uint16_t* Qd = (uint16_t*)alloc(8192ull * 1024 * 2);
  uint16_t* Kd = (uint16_t*)alloc(8192ull * 1024 * 2);
  uint16_t* Vt = (uint16_t*)alloc(8192ull * 1024 * 2);     // V transposed [bh][64][2048]
  uint16_t* Qg = (uint16_t*)alloc(64ull * 32 * 64 * 2);
  uint16_t* Kg = (uint16_t*)alloc(64ull * 32 * 64 * 2);
  uint16_t* Vtg = (uint16_t*)alloc(64ull * 64 * 32 * 2);
  uint16_t* O = xb;  // alias: xb dead after GEMM1

  k_prep<<<9472, 256, 0, stream>>>(x, xb, W_qkv, wqkvt, W_out, woutt, rc, rs);

  gemmQKV<<<dim3(24, 64), 256, 0, stream>>>(xb, wqkvt, 8192, 3072, 1024,
                                            Qd, Kd, Vt, rc, rs);

  k_gather<<<64, 256, 0, stream>>>(Qd, Kd, Vt, Qg, Kg, Vtg);

  attn_fused<<<1088, 256, 0, stream>>>(Qd, Kd, Vt, Kg, Vtg, Qg, O);

  gemm128<<<dim3(8, 64), 256, 0, stream>>>(O, woutt, 8192, 1024, 1024,
                                           (float*)d_out, b_out);
}

// Round 14
// 154.314 us; speedup vs baseline: 1.3489x; 1.0185x over previous
//
#include <hip/hip_runtime.h>
#include <cstdint>

#define DEV __device__ __forceinline__

typedef __bf16 bf16x8 __attribute__((ext_vector_type(8)));
typedef float f32x4 __attribute__((ext_vector_type(4)));
typedef float f32x16 __attribute__((ext_vector_type(16)));
typedef uint32_t u32x4 __attribute__((ext_vector_type(4)));

// ---------- bf16 helpers (RNE) ----------
DEV uint16_t f2b(float f) {
  uint32_t u = __builtin_bit_cast(uint32_t, f);
  u = u + 0x7fffu + ((u >> 16) & 1u);
  return (uint16_t)(u >> 16);
}
DEV float b2f(uint16_t h) { return __builtin_bit_cast(float, (uint32_t)h << 16); }
DEV uint32_t pk2(float lo, float hi) {
  return (uint32_t)f2b(lo) | ((uint32_t)f2b(hi) << 16);
}

DEV f32x16 mfma32(bf16x8 a, bf16x8 b, f32x16 c) {
  return __builtin_amdgcn_mfma_f32_32x32x16_bf16(a, b, c, 0, 0, 0);
}

// ---------- async global->LDS (16B per lane) ----------
DEV void gload16(const void* g, void* s) {
  __builtin_amdgcn_global_load_lds((const __attribute__((address_space(1))) uint32_t*)g,
                                   (__attribute__((address_space(3))) uint32_t*)s, 16, 0, 0);
}

// ---------- fused prep: x->bf16 | W_qkv^T | W_out^T | rope tables ----------
__global__ __launch_bounds__(256) void k_prep(const float* __restrict__ X,
                                              uint16_t* __restrict__ Xb,
                                              const float* __restrict__ Wqkv,
                                              uint16_t* __restrict__ Wqkvt,
                                              const float* __restrict__ Wout,
                                              uint16_t* __restrict__ Woutt,
                                              float* __restrict__ rc,
                                              float* __restrict__ rs) {
  __shared__ uint16_t sh[64][68];
  const int tid = threadIdx.x;
  const int blk = blockIdx.x;
  if (blk < 8192) {
    const int i = blk * 256 + tid;
    float4 v = ((const float4*)X)[i];
    uint64_t packed = (uint64_t)f2b(v.x) | ((uint64_t)f2b(v.y) << 16) |
                      ((uint64_t)f2b(v.z) << 32) | ((uint64_t)f2b(v.w) << 48);
    ((uint64_t*)Xb)[i] = packed;
  } else if (blk < 9216) {
    const bool big = blk < 8960;
    const int t = big ? (blk - 8192) : (blk - 8960);
    const int ntx = big ? 48 : 16;
    const int C = big ? 3072 : 1024;
    const int R = 1024;
    const float* W = big ? Wqkv : Wout;
    uint16_t* Wt = big ? Wqkvt : Woutt;
    const int bc = (t % ntx) * 64, br = (t / ntx) * 64;
#pragma unroll
    for (int it = 0; it < 16; ++it) {
      const int e = it * 256 + tid;
      const int i = e >> 6, j = e & 63;
      sh[j][i] = f2b(W[(size_t)(br + i) * C + bc + j]);
    }
    __syncthreads();
#pragma unroll
    for (int it = 0; it < 2; ++it) {
      const int e = it * 256 + tid;
      const int j = e >> 3, i8 = (e & 7) * 8;
      uint16_t tmp[8];
#pragma unroll
      for (int k = 0; k < 8; ++k) tmp[k] = sh[j][i8 + k];
      *(uint4*)&Wt[(size_t)(bc + j) * R + br + i8] = *(uint4*)tmp;
    }
  } else {
    const int idx = (blk - 9216) * 256 + tid;  // T*32
    const int t = idx >> 5, j = idx & 31;
    float inv = powf(10000.f, -(float)j / 32.f);
    float ang = (float)t * inv;
    rc[idx] = cosf(ang);
    rs[idx] = sinf(ang);
  }
}

// Gather global-key/query tiles: Kg/Qg[bh][32][64], Vtg[bh][64 d][32 g]
__global__ __launch_bounds__(256) void k_gather(const uint16_t* __restrict__ Qd,
                                                const uint16_t* __restrict__ Kd,
                                                const uint16_t* __restrict__ V2,
                                                uint16_t* __restrict__ Qg,
                                                uint16_t* __restrict__ Kg,
                                                uint16_t* __restrict__ Vtg) {
  const int tid = threadIdx.x;
  const int bh = blockIdx.x;
  {
    const int g = tid >> 3, d8 = (tid & 7) * 8;
    const size_t src = ((size_t)(bh << 11) + g * 64) * 64 + d8;
    const size_t dst = ((size_t)bh * 32 + g) * 64 + d8;
    *(uint4*)&Kg[dst] = *(const uint4*)&Kd[src];
    *(uint4*)&Qg[dst] = *(const uint4*)&Qd[src];
  }
  {
    // global key g (t=64g) lives in tile gkt=2g at k=0; V2[bh][gkt][d][k=32]
    const int d = tid >> 2, g8 = (tid & 3) * 8;
    uint16_t tmp[8];
#pragma unroll
    for (int j = 0; j < 8; ++j)
      tmp[j] = V2[(((size_t)bh * 64 + 2 * (g8 + j)) * 64 + d) * 32];
    *(uint4*)&Vtg[((size_t)bh * 64 + d) * 32 + g8] = *(uint4*)tmp;
  }
}

// ---------- 128x128 single-buffer 2-phase bf16 MFMA GEMM1 (round-11 exact K-loop) ----------
// XCD-chunked bm-fastest. Epilogue: Q/K RoPE scattered stores (proven); V blocks
// LDS-bounce -> tiled V2[bh][kt=64][d=64][k=32] (4KB contiguous per 32-key tile,
// so attention's PV B-loads are block-local instead of 4KB-strided scatter).
__global__ __launch_bounds__(256) void gemmQKV(
    const uint16_t* __restrict__ A, const uint16_t* __restrict__ Bt,
    int M, int N, int K,
    uint16_t* __restrict__ Qd, uint16_t* __restrict__ Kd, uint16_t* __restrict__ V2,
    const float* __restrict__ rc, const float* __restrict__ rs) {
  __shared__ __align__(16) uint16_t smem[2 * 128 * 64];  // sA | sB; reused for V transpose
  uint16_t* sA = smem;
  uint16_t* sB = smem + 128 * 64;
  const int tid = threadIdx.x;
  const int w = tid >> 6, lane = tid & 63;
  const int wm = w >> 1, wn = w & 1;
  const int ln = lane & 31, hi = lane >> 5;

  // XCD chunk (nwg=1536, 192/XCD): 8 bm-rows per XCD, bm-fastest order.
  const int orig = blockIdx.y * 24 + blockIdx.x;
  const int xcd = orig & 7, q = orig >> 3;
  const int bm = (xcd * 8 + (q & 7)) * 128;
  const int bn = (q >> 3) * 128;

  f32x16 acc[2][2] = {};
  const int lsw = (ln & 7) << 4;  // read-side XOR swizzle (byte)

  for (int kt = 0; kt < K; kt += 64) {
#pragma unroll
    for (int r = 0; r < 4; ++r) {
      const int slot = r * 256 + tid;
      const int row = slot >> 3, c8 = slot & 7;
      const int gc = kt + ((c8 ^ (row & 7)) << 3);  // pre-swizzled source column
      gload16(A + (size_t)(bm + row) * K + gc, (char*)sA + (r * 256 + (tid & ~63)) * 16);
      gload16(Bt + (size_t)(bn + row) * K + gc, (char*)sB + (r * 256 + (tid & ~63)) * 16);
    }
    __syncthreads();
#pragma unroll
    for (int ks = 0; ks < 4; ++ks) {
      const int cb = ks * 32 + hi * 16;
      bf16x8 af[2], bf[2];
#pragma unroll
      for (int mi = 0; mi < 2; ++mi) {
        const int row = wm * 64 + mi * 32 + ln;
        af[mi] = *(const bf16x8*)((const char*)sA + row * 128 + (cb ^ lsw));
      }
#pragma unroll
      for (int ni = 0; ni < 2; ++ni) {
        const int row = wn * 64 + ni * 32 + ln;
        bf[ni] = *(const bf16x8*)((const char*)sB + row * 128 + (cb ^ lsw));
      }
#pragma unroll
      for (int mi = 0; mi < 2; ++mi)
#pragma unroll
        for (int ni = 0; ni < 2; ++ni)
          acc[mi][ni] = mfma32(af[mi], bf[ni], acc[mi][ni]);
    }
    __syncthreads();
  }

  // C layout (32x32): col = lane&31, row = (r&3) + 8*(r>>2) + 4*hi
  if (bn >= 2048) {
    // ---- V block: LDS-bounce, store tiled V2[bh][kt][64 d][32 k] ----
#pragma unroll
    for (int mi = 0; mi < 2; ++mi)
#pragma unroll
      for (int ni = 0; ni < 2; ++ni) {
        const int col = wn * 64 + ni * 32 + ln;
#pragma unroll
        for (int r = 0; r < 16; ++r) {
          const int crow = (r & 3) + 8 * (r >> 2) + 4 * hi;
          smem[(wm * 64 + mi * 32 + crow) * 128 + col] = f2b(acc[mi][ni][r]);
        }
      }
    __syncthreads();
    const int b = bm >> 11, t0 = bm & 2047;
    const int hbase = (bn - 2048) >> 6;
#pragma unroll
    for (int it = 0; it < 8; ++it) {
      const int idx = it * 256 + tid;
      const int k8 = idx & 3, d = (idx >> 2) & 63;
      const int rest = idx >> 8;             // 0..7
      const int hcol = rest & 1, kt4 = rest >> 1;  // 2 heads x 4 sub-tiles
      uint16_t tmp[8];
#pragma unroll
      for (int j = 0; j < 8; ++j)
        tmp[j] = smem[(kt4 * 32 + k8 * 8 + j) * 128 + hcol * 64 + d];
      const int bh = b * 16 + hbase + hcol;
      const int gkt = (t0 >> 5) + kt4;
      *(uint4*)&V2[(((size_t)bh * 64 + gkt) * 64 + d) * 32 + k8 * 8] = *(uint4*)tmp;
    }
  } else {
    // ---- Q/K block: RoPE + split-store (round-9 proven scattered stores) ----
#pragma unroll
    for (int mi = 0; mi < 2; ++mi) {
#pragma unroll
      for (int ni = 0; ni < 2; ++ni) {
        const int colb = bn + wn * 64 + ni * 32 + ln;
#pragma unroll
        for (int r = 0; r < 16; ++r) {
          const int crow = (r & 3) + 8 * (r >> 2) + 4 * hi;
          const int row = bm + wm * 64 + mi * 32 + crow;
          float val = acc[mi][ni][r];
          const int b = row >> 11, t = row & 2047;
          const float pv = __shfl_xor(val, 1);  // partner column (d^1)
          const int d = colb & 63, j = d >> 1;
          const float c = rc[t * 32 + j], s = rs[t * 32 + j];
          const float rv = (d & 1) ? (val * c + pv * s) : (val * c - pv * s);
          const int cc = colb & 1023, h = cc >> 6;
          uint16_t* dst = (colb < 1024) ? Qd : Kd;
          dst[((((size_t)b * 16 + h) * 2048 + t) << 6) + d] = f2b(rv);
        }
      }
    }
  }
}

// ---------- 128x128 single-buffer 2-phase GEMM2 + bm-fastest XCD chunk ----------
__global__ __launch_bounds__(256) void gemm128(
    const uint16_t* __restrict__ A, const uint16_t* __restrict__ Bt,
    int M, int N, int K, float* __restrict__ Cout, const float* __restrict__ bias) {
  __shared__ __align__(16) uint16_t sA[128 * 64];
  __shared__ __align__(16) uint16_t sB[128 * 64];
  const int tid = threadIdx.x;
  const int w = tid >> 6, lane = tid & 63;
  const int wm = w >> 1, wn = w & 1;
  const int ln = lane & 31, hi = lane >> 5;

  // XCD chunk (nwg=512, 64/XCD): 8 bm x 8 bn per XCD, bm-fastest (4MB set fits L2).
  const int orig = blockIdx.y * 8 + blockIdx.x;
  const int xcd = orig & 7, q = orig >> 3;
  const int bm = (xcd * 8 + (q & 7)) * 128;
  const int bn = (q >> 3) * 128;

  f32x16 acc[2][2] = {};
  const int lsw = (ln & 7) << 4;

  for (int kt = 0; kt < K; kt += 64) {
#pragma unroll
    for (int r = 0; r < 4; ++r) {
      const int slot = r * 256 + tid;
      const int row = slot >> 3, c8 = slot & 7;
      const int gc = kt + ((c8 ^ (row & 7)) << 3);
      gload16(A + (size_t)(bm + row) * K + gc, (char*)sA + (r * 256 + (tid & ~63)) * 16);
      gload16(Bt + (size_t)(bn + row) * K + gc, (char*)sB + (r * 256 + (tid & ~63)) * 16);
    }
    __syncthreads();
#pragma unroll
    for (int ks = 0; ks < 4; ++ks) {
      const int cb = ks * 32 + hi * 16;
      bf16x8 af[2], bf[2];
#pragma unroll
      for (int mi = 0; mi < 2; ++mi) {
        const int row = wm * 64 + mi * 32 + ln;
        af[mi] = *(const bf16x8*)((const char*)sA + row * 128 + (cb ^ lsw));
      }
#pragma unroll
      for (int ni = 0; ni < 2; ++ni) {
        const int row = wn * 64 + ni * 32 + ln;
        bf[ni] = *(const bf16x8*)((const char*)sB + row * 128 + (cb ^ lsw));
      }
#pragma unroll
      for (int mi = 0; mi < 2; ++mi)
#pragma unroll
        for (int ni = 0; ni < 2; ++ni)
          acc[mi][ni] = mfma32(af[mi], bf[ni], acc[mi][ni]);
    }
    __syncthreads();
  }

#pragma unroll
  for (int mi = 0; mi < 2; ++mi) {
#pragma unroll
    for (int ni = 0; ni < 2; ++ni) {
      const int colb = bn + wn * 64 + ni * 32 + ln;
#pragma unroll
      for (int r = 0; r < 16; ++r) {
        const int crow = (r & 3) + 8 * (r >> 2) + 4 * hi;
        const int row = bm + wm * 64 + mi * 32 + crow;
        Cout[(size_t)row * N + colb] = acc[mi][ni][r] + bias[colb];
      }
    }
  }
}

// ---------- MFMA flash-attention tile step (32x32x16, swapped QK^T) ----------
// v_ptr points at a [64 d][32 k] tile (4KB contiguous) — coalesced B-loads.
template <int MASK>
DEV void attn_tile(const uint16_t* __restrict__ kb_ptr, const uint16_t* __restrict__ v_ptr,
                   const int kb, const int qv, const int hi, const int ln,
                   const bf16x8 qf[4], float& m, float& l, f32x16& acc0, f32x16& acc1) {
  bf16x8 kf0 = *(const bf16x8*)&kb_ptr[ln * 64 + 0 + hi * 8];
  bf16x8 kf1 = *(const bf16x8*)&kb_ptr[ln * 64 + 16 + hi * 8];
  bf16x8 kf2 = *(const bf16x8*)&kb_ptr[ln * 64 + 32 + hi * 8];
  bf16x8 kf3 = *(const bf16x8*)&kb_ptr[ln * 64 + 48 + hi * 8];
  bf16x8 vf00 = *(const bf16x8*)&v_ptr[ln * 32 + hi * 8];
  bf16x8 vf01 = *(const bf16x8*)&v_ptr[ln * 32 + 16 + hi * 8];
  bf16x8 vf10 = *(const bf16x8*)&v_ptr[(32 + ln) * 32 + hi * 8];
  bf16x8 vf11 = *(const bf16x8*)&v_ptr[(32 + ln) * 32 + 16 + hi * 8];

  f32x16 sv = {};
  sv = mfma32(kf0, qf[0], sv);
  sv = mfma32(kf1, qf[1], sv);
  sv = mfma32(kf2, qf[2], sv);
  sv = mfma32(kf3, qf[3], sv);

  float s[16];
  float pm = -3.0e38f;
#pragma unroll
  for (int r = 0; r < 16; ++r) {
    const int crow = (r & 3) + 8 * (r >> 2) + 4 * hi;
    bool ok;
    if (MASK == 0) {
      const int key = kb + crow;
      ok = (key <= qv) && (key + 127 >= qv);
    } else if (MASK == 1) {
      ok = crow * 64 <= qv - 128;
    } else {
      const int key = kb + crow;
      ok = (key <= qv);
    }
    s[r] = ok ? sv[r] * 0.125f : -3.0e38f;
    pm = fmaxf(pm, s[r]);
  }
  pm = fmaxf(pm, __shfl_xor(pm, 32));

  if (__any(pm > m + 8.0f)) {
    const float mn = fmaxf(m, pm);
    const float f = __expf(m - mn);
#pragma unroll
    for (int r = 0; r < 16; ++r) {
      const int crow = (r & 3) + 8 * (r >> 2) + 4 * hi;
      const float fr = __shfl(f, crow);
      acc0[r] *= fr;
      acc1[r] *= fr;
    }
    l *= f;
    m = mn;
  }

  float p[16];
  float ps = 0.f;
#pragma unroll
  for (int r = 0; r < 16; ++r) {
    p[r] = __expf(s[r] - m);
    ps += p[r];
  }
  l += ps + __shfl_xor(ps, 32);

  const uint32_t q0a = pk2(p[0], p[1]), q0b = pk2(p[2], p[3]);
  const uint32_t q1a = pk2(p[4], p[5]), q1b = pk2(p[6], p[7]);
  const uint32_t q2a = pk2(p[8], p[9]), q2b = pk2(p[10], p[11]);
  const uint32_t q3a = pk2(p[12], p[13]), q3b = pk2(p[14], p[15]);
  const uint32_t p0a = __shfl_xor(q0a, 32), p0b = __shfl_xor(q0b, 32);
  const uint32_t p1a = __shfl_xor(q1a, 32), p1b = __shfl_xor(q1b, 32);
  const uint32_t p2a = __shfl_xor(q2a, 32), p2b = __shfl_xor(q2b, 32);
  const uint32_t p3a = __shfl_xor(q3a, 32), p3b = __shfl_xor(q3b, 32);
  u32x4 f0, f1;
  f0[0] = hi ? p1a : q0a; f0[1] = hi ? p1b : q0b; f0[2] = hi ? q1a : p0a; f0[3] = hi ? q1b : p0b;
  f1[0] = hi ? p3a : q2a; f1[1] = hi ? p3b : q2b; f1[2] = hi ? q3a : p2a; f1[3] = hi ? q3b : p2b;
  const bf16x8 pa0 = __builtin_bit_cast(bf16x8, f0);
  const bf16x8 pa1 = __builtin_bit_cast(bf16x8, f1);

  acc0 = mfma32(pa0, vf00, acc0);
  acc0 = mfma32(pa1, vf01, acc0);
  acc1 = mfma32(pa0, vf10, acc1);
  acc1 = mfma32(pa1, vf11, acc1);
}

// Fused attention: blocks [0,1024) = main sparse path (skips stores of global-query
// rows); blocks [1024,1088) = full-causal global-query rows (sole writer of those rows).
__global__ __launch_bounds__(256) void attn_fused(const uint16_t* __restrict__ Qd,
                                                  const uint16_t* __restrict__ Kd,
                                                  const uint16_t* __restrict__ V2,
                                                  const uint16_t* __restrict__ Kg,
                                                  const uint16_t* __restrict__ Vtg,
                                                  const uint16_t* __restrict__ Qg,
                                                  uint16_t* __restrict__ O) {
  __shared__ float accL[4][32][64];
  __shared__ float mL[4][32];
  __shared__ float lL[4][32];
  const int tid = threadIdx.x;
  const int lane = tid & 63, hi = lane >> 5, ln = lane & 31;

  if (blockIdx.x < 1024) {
    // ---- main sparse path ----
    const int wid = blockIdx.x * 4 + (tid >> 6);
    const int bh = wid >> 6, qt = wid & 63;
    const int qb = qt * 32;
    const int qv = qb + ln;

    bf16x8 qf[4];
#pragma unroll
    for (int i = 0; i < 4; ++i)
      qf[i] = *(const bf16x8*)&Qd[((size_t)(bh << 11) + qv) * 64 + i * 16 + hi * 8];

    float m = -1e30f, l = 0.f;
    f32x16 acc0 = {}, acc1 = {};

    const int kb0 = qb >= 128 ? qb - 128 : 0;
    for (int kbb = kb0; kbb <= qb; kbb += 32)
      attn_tile<0>(Kd + ((size_t)(bh << 11) + kbb) * 64,
                   V2 + ((size_t)bh * 64 + (kbb >> 5)) * 2048,
                   kbb, qv, hi, ln, qf, m, l, acc0, acc1);
    if (qb >= 128)
      attn_tile<1>(Kg + (size_t)bh * 32 * 64, Vtg + (size_t)bh * 2048,
                   0, qv, hi, ln, qf, m, l, acc0, acc1);

    const float linv = 1.0f / l;
    const int b = bh >> 4, h = bh & 15;
    const int ocol = h * 64 + ln;
    const bool hasg = (qb & 63) == 0;  // this tile contains a global query row (crow 0)
#pragma unroll
    for (int r = 0; r < 16; ++r) {
      const int crow = (r & 3) + 8 * (r >> 2) + 4 * hi;
      // __shfl under FULL exec (divergent skip before it would read an inactive lane).
      const float sc = __shfl(linv, crow);
      if (hasg && crow == 0) continue;  // attn-global branch owns this row
      const size_t orow = (size_t)(b * 2048 + qb + crow);
      O[orow * 1024 + ocol] = f2b(acc0[r] * sc);
      O[orow * 1024 + ocol + 32] = f2b(acc1[r] * sc);
    }
  } else {
    // ---- global-query rows (t%64==0): full causal, 4 waves split K, LDS merge ----
    const int bh = blockIdx.x - 1024;
    const int wv = tid >> 6;
    const int qv = ln * 64;

    bf16x8 qf[4];
#pragma unroll
    for (int i = 0; i < 4; ++i)
      qf[i] = *(const bf16x8*)&Qg[((size_t)bh * 32 + ln) * 64 + i * 16 + hi * 8];

    float m = -1e30f, l = 0.f;
    f32x16 acc0 = {}, acc1 = {};
    for (int kt = wv; kt < 64; kt += 4) {
      const int kbb = kt * 32;
      attn_tile<2>(Kd + ((size_t)(bh << 11) + kbb) * 64,
                   V2 + ((size_t)bh * 64 + kt) * 2048,
                   kbb, qv, hi, ln, qf, m, l, acc0, acc1);
    }

    if (hi == 0) {
      mL[wv][ln] = m;
      lL[wv][ln] = l;
    }
#pragma unroll
    for (int r = 0; r < 16; ++r) {
      const int crow = (r & 3) + 8 * (r >> 2) + 4 * hi;
      accL[wv][crow][ln] = acc0[r];
      accL[wv][crow][ln + 32] = acc1[r];
    }
    __syncthreads();

    const int q = tid >> 3, d0 = (tid & 7) * 8;
    float M = fmaxf(fmaxf(mL[0][q], mL[1][q]), fmaxf(mL[2][q], mL[3][q]));
    float L = 0.f;
    float v[8] = {};
#pragma unroll
    for (int w = 0; w < 4; ++w) {
      const float ew = __expf(mL[w][q] - M);
      L += lL[w][q] * ew;
#pragma unroll
      for (int j = 0; j < 8; ++j) v[j] += accL[w][q][d0 + j] * ew;
    }
    const float Li = 1.0f / L;
    const int b = bh >> 4, h = bh & 15;
    const size_t orow = (size_t)(b * 2048 + q * 64);
#pragma unroll
    for (int j = 0; j < 8; ++j) O[orow * 1024 + h * 64 + d0 + j] = f2b(v[j] * Li);
  }
}

// ---------- launch ----------
extern "C" void kernel_launch(void* const* d_in, const int* in_sizes, int n_in,
                              void* d_out, int out_size, void* d_ws, size_t ws_size,
                              hipStream_t stream) {
  const float* x = (const float*)d_in[0];
  const float* W_qkv = (const float*)d_in[1];
  const float* W_out = (const float*)d_in[2];
  const float* b_out = (const float*)d_in[3];

  char* ws = (char*)d_ws;
  size_t off = 0;
  auto alloc = [&](size_t bytes) {
    void* p = ws + off;
    off += (bytes + 255) & ~(size_t)255;
    return p;
  };
  uint16_t* xb = (uint16_t*)alloc(8192ull * 1024 * 2);     // x bf16 (reused as attn-out O)
  uint16_t* wqkvt = (uint16_t*)alloc(3072ull * 1024 * 2);  // W_qkv^T bf16
  uint16_t* woutt = (uint16_t*)alloc(1024ull * 1024 * 2);  // W_out^T bf16
  float* rc = (float*)alloc(2048ull * 32 * 4);
  float* rs = (float*)alloc(2048ull * 32 * 4);
  uint16_t* Qd = (uint16_t*)alloc(8192ull * 1024 * 2);
  uint16_t* Kd = (uint16_t*)alloc(8192ull * 1024 * 2);
  uint16_t* V2 = (uint16_t*)alloc(8192ull * 1024 * 2);     // V tiled [bh][kt][64 d][32 k]
  uint16_t* Qg = (uint16_t*)alloc(64ull * 32 * 64 * 2);
  uint16_t* Kg = (uint16_t*)alloc(64ull * 32 * 64 * 2);
  uint16_t* Vtg = (uint16_t*)alloc(64ull * 64 * 32 * 2);
  uint16_t* O = xb;  // alias: xb dead after GEMM1

  k_prep<<<9472, 256, 0, stream>>>(x, xb, W_qkv, wqkvt, W_out, woutt, rc, rs);

  gemmQKV<<<dim3(24, 64), 256, 0, stream>>>(xb, wqkvt, 8192, 3072, 1024,
                                            Qd, Kd, V2, rc, rs);

  k_gather<<<64, 256, 0, stream>>>(Qd, Kd, V2, Qg, Kg, Vtg);

  attn_fused<<<1088, 256, 0, stream>>>(Qd, Kd, V2, Kg, Vtg, Qg, O);

  gemm128<<<dim3(8, 64), 256, 0, stream>>>(O, woutt, 8192, 1024, 1024,
                                           (float*)d_out, b_out);
}